// Round 3
// baseline (3323.116 us; speedup 1.0000x reference)
//
#include <hip/hip_runtime.h>
#include <stdint.h>

#define B_ 32
#define T_ 512
#define E_ 1024
#define H_ 1024
#define NWAVE 64   // k_rnn: 64 blocks x 1 wave; wave j owns h-cols [16j,16j+16)

typedef __attribute__((ext_vector_type(8))) short short8;
typedef __attribute__((ext_vector_type(4))) float floatx4;
typedef __attribute__((ext_vector_type(4))) int int4v;

__device__ __forceinline__ unsigned short bf16_of(float f) {
    unsigned u = __float_as_uint(f);
    return (unsigned short)((u + 0x8000u) >> 16);   // round-half-up to bf16
}

__device__ __forceinline__ short8 load_bf8(const float* __restrict__ p) {
    const float4* q = (const float4*)p;
    float4 v0 = q[0];
    float4 v1 = q[1];
    short8 r;
    r[0] = (short)bf16_of(v0.x); r[1] = (short)bf16_of(v0.y);
    r[2] = (short)bf16_of(v0.z); r[3] = (short)bf16_of(v0.w);
    r[4] = (short)bf16_of(v1.x); r[5] = (short)bf16_of(v1.y);
    r[6] = (short)bf16_of(v1.z); r[7] = (short)bf16_of(v1.w);
    return r;
}

// ---------------------------------------------------------------------------
// K1: xp[n,h] = sum_e x[n,e] * Wih[h,e] + (bih[h]+bhh[h]),  n = b*T+t
// (unchanged — isolate the k_rnn experiment)
// ---------------------------------------------------------------------------
__global__ __launch_bounds__(256) void k_xp(const float* __restrict__ x,
                                            const float* __restrict__ Wih,
                                            const float* __restrict__ bih,
                                            const float* __restrict__ bhh,
                                            float* __restrict__ out) {
    const int tid  = threadIdx.x;
    const int w    = tid >> 6;
    const int lane = tid & 63;
    const int l15  = lane & 15;
    const int quad = lane >> 4;
    const int rb = blockIdx.x & 127;
    const int cb = blockIdx.x >> 7;
    const int row_base = rb * 128 + w * 32;
    const int col_base = cb * 128;

    floatx4 acc[2][8];
#pragma unroll
    for (int i = 0; i < 2; i++)
#pragma unroll
        for (int j = 0; j < 8; j++) acc[i][j] = (floatx4)0.0f;

    for (int k0 = 0; k0 < E_; k0 += 32) {
        const int koff = k0 + quad * 8;
        short8 a[2];
#pragma unroll
        for (int mt = 0; mt < 2; mt++)
            a[mt] = load_bf8(x + (size_t)(row_base + mt * 16 + l15) * E_ + koff);
        short8 b[8];
#pragma unroll
        for (int nt = 0; nt < 8; nt++)
            b[nt] = load_bf8(Wih + (size_t)(col_base + nt * 16 + l15) * E_ + koff);
#pragma unroll
        for (int mt = 0; mt < 2; mt++)
#pragma unroll
            for (int nt = 0; nt < 8; nt++)
                acc[mt][nt] = __builtin_amdgcn_mfma_f32_16x16x32_bf16(
                    a[mt], b[nt], acc[mt][nt], 0, 0, 0);
    }

#pragma unroll
    for (int nt = 0; nt < 8; nt++) {
        const int col = col_base + nt * 16 + l15;
        const float bias = bih[col] + bhh[col];
#pragma unroll
        for (int mt = 0; mt < 2; mt++) {
            const int row = row_base + mt * 16 + quad * 4;
#pragma unroll
            for (int r = 0; r < 4; r++)
                out[(size_t)(row + r) * H_ + col] = acc[mt][nt][r] + bias;
        }
    }
}

// ---------------------------------------------------------------------------
// K2: zero ws: h ping-pong (2 x 64KB blocked bf16 = 32768 u32) + 64 flags
// (64B stride = 1024 u32). Total 33792 u32 -> 132 blocks x 256.
// ---------------------------------------------------------------------------
__global__ void k_init(unsigned* __restrict__ ws) {
    const int i = blockIdx.x * blockDim.x + threadIdx.x;
    if (i < 33792) ws[i] = 0u;
}

// ---------------------------------------------------------------------------
// K3 v3: wave-dataflow recurrence with MFMA-fragment-blocked h exchange.
//
// Exchange layout (16B units): hL[(c*2+mt)*64 + lane], c = k-chunk (0..31),
// mt = batch-tile (0..1). Consumer's A-fragment for (c,mt) is exactly
// hL[(c*2+mt)*64 + lane] -> every load instr is a contiguous 1KB burst
// (vs round-2's 16 lines x 2KB stride = ~1024 scattered LLC misses/step).
//
// Producer (wave wid owns cols [16wid,16wid+16)): D-layout h -> 1KB LDS
// transpose (single wave, lgkmcnt only) -> each lane holds one 16B A-layout
// chunk: mt=lane>>5, sub=(lane>>4)&1, m=lane&15 covers (batch mt*16+m,
// cols j0+8*sub..+8) -> slot (wid>>1)*128 + mt*64 + (wid&1)*32 + sub*16 + m.
// Stored as 4 agent-scope u32 atomic stores (write-through, same mechanism
// as round 2), vmcnt(0), flag. fp32 out stores AFTER the flag (off the
// cross-wave critical path).
// ---------------------------------------------------------------------------
__global__ __launch_bounds__(64, 1) void k_rnn(const float* __restrict__ Whh,
                                               float* __restrict__ out,
                                               unsigned* __restrict__ ws) {
    const int lane = threadIdx.x;     // 0..63
    const int l15  = lane & 15;
    const int quad = lane >> 4;
    const int wid  = blockIdx.x;      // 0..63
    const int j0   = wid * 16;

    unsigned short* hb    = (unsigned short*)ws;   // 2 x 64KB blocked bf16
    unsigned*       flags = ws + 32768;            // 64 flags, 64B stride

    // Producer store slot (16B units) and LDS transpose read offset (bytes).
    const int mt_s = lane >> 5;
    const int sub  = (lane >> 4) & 1;
    const int m_s  = lane & 15;
    const int slot = (wid >> 1) * 128 + mt_s * 64 + (wid & 1) * 32 + sub * 16 + m_s;
    const int lds_off = mt_s * 512 + m_s * 32 + sub * 16;

    __shared__ unsigned short sh[512];   // [batch 0..31][col 0..15]

    // Full-K W_hh B-fragments: wreg[c] covers k in [32c + quad*8, +8), col j0+l15.
    short8 wreg[32];
#pragma unroll
    for (int c = 0; c < 32; c++)
        wreg[c] = load_bf8(Whh + (size_t)(j0 + l15) * H_ + c * 32 + quad * 8);

#pragma unroll 1
    for (int t = 0; t < T_; t++) {
        const short8* hc = (const short8*)(hb + (size_t)(t & 1) * (B_ * H_));
        unsigned*     nx = (unsigned*)(hb + (size_t)((t + 1) & 1) * (B_ * H_));

        // xp prefetch (independent of h): batch = mt*16+quad*4+r, col = j0+l15
        float xv[2][4];
#pragma unroll
        for (int mt = 0; mt < 2; mt++)
#pragma unroll
            for (int r = 0; r < 4; r++) {
                const int b = mt * 16 + quad * 4 + r;
                xv[mt][r] = out[((size_t)b * T_ + t) * H_ + j0 + l15];
            }

        if (t > 0) {
            const unsigned tv = (unsigned)t;
            while (true) {
                unsigned v = __hip_atomic_load(&flags[lane * 16], __ATOMIC_RELAXED,
                                               __HIP_MEMORY_SCOPE_AGENT);
                if (__ballot(v < tv) == 0ull) break;
            }
            __builtin_amdgcn_fence(__ATOMIC_ACQUIRE, "agent");  // inv stale L1/L2
        }

        floatx4 acc[2];
        acc[0] = (floatx4)0.0f;
        acc[1] = (floatx4)0.0f;
#pragma unroll
        for (int c = 0; c < 32; c++) {
#pragma unroll
            for (int mt = 0; mt < 2; mt++) {
                short8 ah = hc[(c * 2 + mt) * 64 + lane];   // 1KB coalesced burst
                acc[mt] = __builtin_amdgcn_mfma_f32_16x16x32_bf16(ah, wreg[c],
                                                                  acc[mt], 0, 0, 0);
            }
        }

        // tanh in-register (D layout: col=l15, batch=mt*16+quad*4+r),
        // bf16 -> LDS transpose to A-layout.
        float hv[2][4];
#pragma unroll
        for (int mt = 0; mt < 2; mt++)
#pragma unroll
            for (int r = 0; r < 4; r++) {
                const float p = xv[mt][r] + acc[mt][r];
                const float h = 1.0f - 2.0f / (__expf(2.0f * p) + 1.0f);
                hv[mt][r] = h;
                sh[(mt * 16 + quad * 4 + r) * 16 + l15] = bf16_of(h);
            }

        // Each lane: one 16B A-layout chunk -> 4 write-through u32 stores.
        int4v tv4 = *(const int4v*)((const char*)sh + lds_off);
#pragma unroll
        for (int i = 0; i < 4; i++)
            __hip_atomic_store(nx + slot * 4 + i, ((unsigned*)&tv4)[i],
                               __ATOMIC_RELAXED, __HIP_MEMORY_SCOPE_AGENT);

        asm volatile("s_waitcnt vmcnt(0)" ::: "memory");
        if (lane == 0)
            __hip_atomic_store(&flags[wid * 16], (unsigned)(t + 1),
                               __ATOMIC_RELAXED, __HIP_MEMORY_SCOPE_AGENT);

        // fp32 outputs: off the cross-wave critical path (drained later).
#pragma unroll
        for (int mt = 0; mt < 2; mt++)
#pragma unroll
            for (int r = 0; r < 4; r++) {
                const int b = mt * 16 + quad * 4 + r;
                out[((size_t)b * T_ + t) * H_ + j0 + l15] = hv[mt][r];
            }
    }
}

// ---------------------------------------------------------------------------
extern "C" void kernel_launch(void* const* d_in, const int* in_sizes, int n_in,
                              void* d_out, int out_size, void* d_ws, size_t ws_size,
                              hipStream_t stream) {
    const float* x   = (const float*)d_in[0];
    const float* Wih = (const float*)d_in[1];
    const float* Whh = (const float*)d_in[2];
    const float* bih = (const float*)d_in[3];
    const float* bhh = (const float*)d_in[4];
    float* out = (float*)d_out;
    unsigned* ws = (unsigned*)d_ws;

    k_init<<<132, 256, 0, stream>>>(ws);
    k_xp<<<128 * 8, 256, 0, stream>>>(x, Wih, bih, bhh, out);
    k_rnn<<<NWAVE, 64, 0, stream>>>(Whh, out, ws);
}

// Round 4
// 2799.565 us; speedup vs baseline: 1.1870x; 1.1870x over previous
//
#include <hip/hip_runtime.h>
#include <stdint.h>

#define B_ 32
#define T_ 512
#define E_ 1024
#define H_ 1024
#define NWAVE 64   // k_rnn: 64 blocks x 1 wave; wave j owns h-cols [16j,16j+16)

typedef __attribute__((ext_vector_type(8))) short short8;
typedef __attribute__((ext_vector_type(4))) float floatx4;
typedef __attribute__((ext_vector_type(4))) int int4v;
typedef unsigned long long ull;

union U16 { ull u[2]; short8 s; int4v v; };

__device__ __forceinline__ unsigned short bf16_of(float f) {
    unsigned u = __float_as_uint(f);
    return (unsigned short)((u + 0x8000u) >> 16);   // round-half-up to bf16
}

__device__ __forceinline__ short8 load_bf8(const float* __restrict__ p) {
    const float4* q = (const float4*)p;
    float4 v0 = q[0];
    float4 v1 = q[1];
    short8 r;
    r[0] = (short)bf16_of(v0.x); r[1] = (short)bf16_of(v0.y);
    r[2] = (short)bf16_of(v0.z); r[3] = (short)bf16_of(v0.w);
    r[4] = (short)bf16_of(v1.x); r[5] = (short)bf16_of(v1.y);
    r[6] = (short)bf16_of(v1.z); r[7] = (short)bf16_of(v1.w);
    return r;
}

// ---------------------------------------------------------------------------
// K1: xp[n,h] = sum_e x[n,e] * Wih[h,e] + (bih[h]+bhh[h])  (unchanged)
// ---------------------------------------------------------------------------
__global__ __launch_bounds__(256) void k_xp(const float* __restrict__ x,
                                            const float* __restrict__ Wih,
                                            const float* __restrict__ bih,
                                            const float* __restrict__ bhh,
                                            float* __restrict__ out) {
    const int tid  = threadIdx.x;
    const int w    = tid >> 6;
    const int lane = tid & 63;
    const int l15  = lane & 15;
    const int quad = lane >> 4;
    const int rb = blockIdx.x & 127;
    const int cb = blockIdx.x >> 7;
    const int row_base = rb * 128 + w * 32;
    const int col_base = cb * 128;

    floatx4 acc[2][8];
#pragma unroll
    for (int i = 0; i < 2; i++)
#pragma unroll
        for (int j = 0; j < 8; j++) acc[i][j] = (floatx4)0.0f;

    for (int k0 = 0; k0 < E_; k0 += 32) {
        const int koff = k0 + quad * 8;
        short8 a[2];
#pragma unroll
        for (int mt = 0; mt < 2; mt++)
            a[mt] = load_bf8(x + (size_t)(row_base + mt * 16 + l15) * E_ + koff);
        short8 b[8];
#pragma unroll
        for (int nt = 0; nt < 8; nt++)
            b[nt] = load_bf8(Wih + (size_t)(col_base + nt * 16 + l15) * E_ + koff);
#pragma unroll
        for (int mt = 0; mt < 2; mt++)
#pragma unroll
            for (int nt = 0; nt < 8; nt++)
                acc[mt][nt] = __builtin_amdgcn_mfma_f32_16x16x32_bf16(
                    a[mt], b[nt], acc[mt][nt], 0, 0, 0);
    }

#pragma unroll
    for (int nt = 0; nt < 8; nt++) {
        const int col = col_base + nt * 16 + l15;
        const float bias = bih[col] + bhh[col];
#pragma unroll
        for (int mt = 0; mt < 2; mt++) {
            const int row = row_base + mt * 16 + quad * 4;
#pragma unroll
            for (int r = 0; r < 4; r++)
                out[(size_t)(row + r) * H_ + col] = acc[mt][nt][r] + bias;
        }
    }
}

// ---------------------------------------------------------------------------
// ws layout (u32 units): [0,1024) flags (64 x 64B-stride); ring slots at
// 1024 + s*16384, each 64KB: lo-half 32KB (j=0..3 of each 16B chunk) then
// hi-half 32KB (j=4..7). Slot ring-1 holds h_{-1}=0.
// ---------------------------------------------------------------------------
__global__ void k_init(unsigned* __restrict__ ws, int ring) {
    const int i = blockIdx.x * blockDim.x + threadIdx.x;   // 0..16383
    if (i < 1024) ws[i] = 0u;
    ws[1024 + (ring - 1) * 16384 + i] = 0u;
}

// ---------------------------------------------------------------------------
// K3 v4: wave-dataflow recurrence, ring-buffered exchange, no per-step L2 inv.
//
// Producer (step t): D-layout h -> 1KB LDS transpose -> each lane one 16B
// A-layout chunk -> TWO u64 agent-atomic stores (write-through to the
// coherence point) into the slot's lo/hi arrays. Lanes' slots are consecutive
// within 16-lane groups -> each store instr covers contiguous 128B-aligned
// full lines (fixes round-3's 16B-stride scatter; WRITE_SIZE amplification).
// Then s_waitcnt vmcnt(0) -> per-wave flag (agent atomic, monotone t+1).
//
// Consumer (step t): lane-parallel poll of 64 flags (atomic loads bypass
// caches -> always fresh), then NORMAL cached 8B loads of the h slot.
// Staleness: a slot line is rewritten only every `ring` steps, and writes
// bypass L2; a cached copy from the previous generation (read at step
// t-ring) is killed by the acquire fence (buffer_inv) executed at every
// t % ring == 0, which falls in (t-ring, t] for every reread. So one fence
// per ring steps suffices; other 7 steps keep L1/L2 warm and let the 8
// waves per XCD share one LLC fetch of the 64KB slot via L2.
// Skew safety: wave at step t passed poll(flags>=t) => all waves completed
// step t-1 incl. their reads of h_{t-2}..; overwrite target slot t%ring
// holds h_{t-ring}, last read at step t-ring+1 <= t-1.  ring>=2 OK.
// ---------------------------------------------------------------------------
__global__ __launch_bounds__(64, 1) void k_rnn(const float* __restrict__ Whh,
                                               float* __restrict__ out,
                                               unsigned* __restrict__ ws,
                                               int ring) {
    const int lane = threadIdx.x;     // 0..63
    const int l15  = lane & 15;
    const int quad = lane >> 4;
    const int wid  = blockIdx.x;      // 0..63
    const int j0   = wid * 16;

    unsigned* flags = ws;             // 64 flags, 64B stride

    // Producer store slot (16B units) and LDS transpose read offset (bytes).
    const int mt_s = lane >> 5;
    const int sub  = (lane >> 4) & 1;
    const int m_s  = lane & 15;
    const int slot = (wid >> 1) * 128 + mt_s * 64 + (wid & 1) * 32 + sub * 16 + m_s;
    const int lds_off = mt_s * 512 + m_s * 32 + sub * 16;

    __shared__ unsigned short sh[512];   // [batch 0..31][col 0..15]

    // Full-K W_hh B-fragments: wreg[c] covers k in [32c + quad*8, +8), col j0+l15.
    short8 wreg[32];
#pragma unroll
    for (int c = 0; c < 32; c++)
        wreg[c] = load_bf8(Whh + (size_t)(j0 + l15) * H_ + c * 32 + quad * 8);

#pragma unroll 1
    for (int t = 0; t < T_; t++) {
        const int rs = (t + ring - 1) & (ring - 1);   // read slot (h_{t-1})
        const int wsl = t & (ring - 1);               // write slot (h_t)
        const ull* hA = (const ull*)(ws + 1024 + rs * 16384);
        const ull* hB = hA + 4096;
        ull* nxA = (ull*)(ws + 1024 + wsl * 16384);
        ull* nxB = nxA + 4096;

        // xp prefetch (independent of h): batch = mt*16+quad*4+r, col = j0+l15
        float xv[2][4];
#pragma unroll
        for (int mt = 0; mt < 2; mt++)
#pragma unroll
            for (int r = 0; r < 4; r++) {
                const int b = mt * 16 + quad * 4 + r;
                xv[mt][r] = out[((size_t)b * T_ + t) * H_ + j0 + l15];
            }

        if (t > 0) {
            const unsigned tv = (unsigned)t;
            while (true) {
                unsigned v = __hip_atomic_load(&flags[lane * 16], __ATOMIC_RELAXED,
                                               __HIP_MEMORY_SCOPE_AGENT);
                if (__ballot(v < tv) == 0ull) break;
            }
            if ((t & (ring - 1)) == 0)
                __builtin_amdgcn_fence(__ATOMIC_ACQUIRE, "agent");  // inv L1+L2
            else
                asm volatile("" ::: "memory");  // compiler barrier: no hoist
        }

        floatx4 acc[2];
        acc[0] = (floatx4)0.0f;
        acc[1] = (floatx4)0.0f;
#pragma unroll
        for (int c = 0; c < 32; c++) {
#pragma unroll
            for (int mt = 0; mt < 2; mt++) {
                U16 u;
                u.u[0] = hA[(c * 2 + mt) * 64 + lane];   // 512B coalesced burst
                u.u[1] = hB[(c * 2 + mt) * 64 + lane];
                acc[mt] = __builtin_amdgcn_mfma_f32_16x16x32_bf16(u.s, wreg[c],
                                                                  acc[mt], 0, 0, 0);
            }
        }

        // tanh in-register (D layout: col=l15, batch=mt*16+quad*4+r),
        // bf16 -> LDS transpose to A-layout (DS ops are in-order per wave).
        float hv[2][4];
#pragma unroll
        for (int mt = 0; mt < 2; mt++)
#pragma unroll
            for (int r = 0; r < 4; r++) {
                const float p = xv[mt][r] + acc[mt][r];
                const float h = 1.0f - 2.0f / (__expf(2.0f * p) + 1.0f);
                hv[mt][r] = h;
                sh[(mt * 16 + quad * 4 + r) * 16 + l15] = bf16_of(h);
            }

        // One 16B A-layout chunk per lane -> 2 coalesced u64 write-through
        // stores (full 128B lines per 16-lane group).
        U16 pk;
        pk.v = *(const int4v*)((const char*)sh + lds_off);
        __hip_atomic_store(nxA + slot, pk.u[0], __ATOMIC_RELAXED,
                           __HIP_MEMORY_SCOPE_AGENT);
        __hip_atomic_store(nxB + slot, pk.u[1], __ATOMIC_RELAXED,
                           __HIP_MEMORY_SCOPE_AGENT);

        asm volatile("s_waitcnt vmcnt(0)" ::: "memory");
        if (lane == 0)
            __hip_atomic_store(&flags[wid * 16], (unsigned)(t + 1),
                               __ATOMIC_RELAXED, __HIP_MEMORY_SCOPE_AGENT);

        // fp32 outputs: off the cross-wave critical path.
#pragma unroll
        for (int mt = 0; mt < 2; mt++)
#pragma unroll
            for (int r = 0; r < 4; r++) {
                const int b = mt * 16 + quad * 4 + r;
                out[((size_t)b * T_ + t) * H_ + j0 + l15] = hv[mt][r];
            }
    }
}

// ---------------------------------------------------------------------------
extern "C" void kernel_launch(void* const* d_in, const int* in_sizes, int n_in,
                              void* d_out, int out_size, void* d_ws, size_t ws_size,
                              hipStream_t stream) {
    const float* x   = (const float*)d_in[0];
    const float* Wih = (const float*)d_in[1];
    const float* Whh = (const float*)d_in[2];
    const float* bih = (const float*)d_in[3];
    const float* bhh = (const float*)d_in[4];
    float* out = (float*)d_out;
    unsigned* ws = (unsigned*)d_ws;

    // ring=8 (fence every 8 steps) needs 4KB flags + 8*64KB = 516KB+.
    // Fallback ring=2 fits the proven 132KB footprint (fence every 2 steps).
    const size_t need8 = (size_t)(1024 + 8 * 16384) * sizeof(unsigned);
    const int ring = (ws_size >= need8) ? 8 : 2;

    k_init<<<64, 256, 0, stream>>>(ws, ring);
    k_xp<<<128 * 8, 256, 0, stream>>>(x, Wih, bih, bhh, out);
    k_rnn<<<NWAVE, 64, 0, stream>>>(Whh, out, ws, ring);
}